// Round 4
// baseline (494.058 us; speedup 1.0000x reference)
//
#include <hip/hip_runtime.h>
#include <hip/hip_bf16.h>
#include <math.h>

#define T_TOK 2048   // BATCH * SEQ
#define DM    1024
#define DI    2048
#define DS    16
#define DR    64
#define E96   96
#define CH    64     // scan chunk length
#define NCH   16     // chunks per sequence (1024 / CH)

typedef __attribute__((ext_vector_type(8))) short bf16x8;
typedef __attribute__((ext_vector_type(4))) float f32x4;

__device__ __forceinline__ float silu_f(float x) {
    return x / (1.f + __expf(-x));
}
__device__ __forceinline__ float softplus_f(float x) {
    return log1pf(__expf(-fabsf(x))) + fmaxf(x, 0.f);
}
__device__ __forceinline__ unsigned short f2bf(float f) {
    unsigned int u = __float_as_uint(f);
    u = (u + 0x7fffu + ((u >> 16) & 1u)) >> 16;
    return (unsigned short)u;
}
__device__ __forceinline__ float bf2f(unsigned short h) {
    return __uint_as_float(((unsigned int)h) << 16);
}
__device__ __forceinline__ void gload16(const unsigned short* g, unsigned short* l) {
    __builtin_amdgcn_global_load_lds((const __attribute__((address_space(1))) void*)g,
                                     (__attribute__((address_space(3))) void*)l, 16, 0, 0);
}

// fp32 -> (hi, lo) bf16 split
__global__ __launch_bounds__(256) void split_kernel(
    const float* __restrict__ in, unsigned short* __restrict__ hi,
    unsigned short* __restrict__ lo, int n4)
{
    int i = blockIdx.x * 256 + threadIdx.x;
    if (i >= n4) return;
    float4 v = ((const float4*)in)[i];
    ushort4 h, l;
    h.x = f2bf(v.x); l.x = f2bf(v.x - bf2f(h.x));
    h.y = f2bf(v.y); l.y = f2bf(v.y - bf2f(h.y));
    h.z = f2bf(v.z); l.z = f2bf(v.z - bf2f(h.z));
    h.w = f2bf(v.w); l.w = f2bf(v.w - bf2f(h.w));
    ((ushort4*)hi)[i] = h;
    ((ushort4*)lo)[i] = l;
}

// Split-bf16 MFMA GEMM (3-term). 128x128 tile, BK=32, 4 waves.
template<int EPI>
__global__ __launch_bounds__(256, 2) void mgemm128(
    const unsigned short* __restrict__ Ah, const unsigned short* __restrict__ Al, int lda,
    const unsigned short* __restrict__ Bh, const unsigned short* __restrict__ Bl, int ldb,
    float* __restrict__ C, int ldc, int K)
{
    __shared__ unsigned short lds[16384];
    const int tid = threadIdx.x;
    const int wid = tid >> 6, lane = tid & 63;
    const int wm = wid >> 1, wn = wid & 1;
    const int bm = blockIdx.y * 128, bn = blockIdx.x * 128;
    const int klen = K / gridDim.z;
    const int kbeg = blockIdx.z * klen, kend = kbeg + klen;

    const int r0  = wid * 32 + (lane >> 2);
    const int r1  = r0 + 16;
    const int sp  = lane & 3;
    const int ks0 = sp ^ ((r0 >> 1) & 3);
    const int ks1 = sp ^ ((r1 >> 1) & 3);
    const size_t ga0 = (size_t)(bm + r0) * lda + ks0 * 8;
    const size_t ga1 = (size_t)(bm + r1) * lda + ks1 * 8;
    const size_t gb0 = (size_t)(bn + r0) * ldb + ks0 * 8;
    const size_t gb1 = (size_t)(bn + r1) * ldb + ks1 * 8;
    unsigned short* lw0 = lds + wid * 1024;
    unsigned short* lw1 = lds + wid * 1024 + 512;

    const int ln = lane & 15, ls = lane >> 4;
    int offA[4], offB[4];
    #pragma unroll
    for (int f = 0; f < 4; ++f) {
        int ra = wm * 64 + f * 16 + ln;
        int rb = wn * 64 + f * 16 + ln;
        offA[f] = ra * 32 + (ls ^ ((ra >> 1) & 3)) * 8;
        offB[f] = rb * 32 + (ls ^ ((rb >> 1) & 3)) * 8;
    }

    f32x4 acc[4][4] = {};
    for (int k0 = kbeg; k0 < kend; k0 += 32) {
        gload16(Ah + ga0 + k0, lw0);
        gload16(Ah + ga1 + k0, lw1);
        gload16(Al + ga0 + k0, lw0 + 4096);
        gload16(Al + ga1 + k0, lw1 + 4096);
        gload16(Bh + gb0 + k0, lw0 + 8192);
        gload16(Bh + gb1 + k0, lw1 + 8192);
        gload16(Bl + gb0 + k0, lw0 + 12288);
        gload16(Bl + gb1 + k0, lw1 + 12288);
        __syncthreads();
        bf16x8 ah[4], al[4], bh[4], bl[4];
        #pragma unroll
        for (int f = 0; f < 4; ++f) {
            ah[f] = *(const bf16x8*)&lds[offA[f]];
            al[f] = *(const bf16x8*)&lds[4096 + offA[f]];
            bh[f] = *(const bf16x8*)&lds[8192 + offB[f]];
            bl[f] = *(const bf16x8*)&lds[12288 + offB[f]];
        }
        #pragma unroll
        for (int i = 0; i < 4; ++i)
            #pragma unroll
            for (int j = 0; j < 4; ++j) {
                acc[i][j] = __builtin_amdgcn_mfma_f32_16x16x32_bf16(ah[i], bh[j], acc[i][j], 0, 0, 0);
                acc[i][j] = __builtin_amdgcn_mfma_f32_16x16x32_bf16(al[i], bh[j], acc[i][j], 0, 0, 0);
                acc[i][j] = __builtin_amdgcn_mfma_f32_16x16x32_bf16(ah[i], bl[j], acc[i][j], 0, 0, 0);
            }
        __syncthreads();
    }

    #pragma unroll
    for (int i = 0; i < 4; ++i) {
        int crow0 = bm + wm * 64 + i * 16 + ls * 4;
        #pragma unroll
        for (int j = 0; j < 4; ++j) {
            int ccol = bn + wn * 64 + j * 16 + ln;
            #pragma unroll
            for (int r = 0; r < 4; ++r) {
                float v = acc[i][j][r];
                if (EPI == 2) atomicAdd(&C[(size_t)(crow0 + r) * ldc + ccol], v);
                else          C[(size_t)(crow0 + r) * ldc + ccol] = v;
            }
        }
    }
}

// fp32 GEMM. EPI==3: C = softplus(C + rowbias[row])  (used for transposed delta)
template<int EPI>
__global__ __launch_bounds__(256) void sgemm128(
    const float* __restrict__ A, int lda,
    const float* __restrict__ B, int ldb,
    float* __restrict__ C, int ldc,
    int K, const float* __restrict__ bias)
{
    __shared__ float As[8][128];
    __shared__ float Bs[8][128];
    const int bm = blockIdx.y * 128, bn = blockIdx.x * 128;
    const int tid = threadIdx.x;
    const int lr = tid >> 1, lk = (tid & 1) * 4;
    const int tx = tid & 15, ty = tid >> 4;
    float acc[8][8] = {};
    const float* Ap = A + (size_t)(bm + lr) * lda + lk;
    const float* Bp = B + (size_t)(bn + lr) * ldb + lk;
    for (int k0 = 0; k0 < K; k0 += 8) {
        float4 av = *(const float4*)(Ap + k0);
        float4 bv = *(const float4*)(Bp + k0);
        __syncthreads();
        As[lk+0][lr] = av.x; As[lk+1][lr] = av.y; As[lk+2][lr] = av.z; As[lk+3][lr] = av.w;
        Bs[lk+0][lr] = bv.x; Bs[lk+1][lr] = bv.y; Bs[lk+2][lr] = bv.z; Bs[lk+3][lr] = bv.w;
        __syncthreads();
        #pragma unroll
        for (int k = 0; k < 8; ++k) {
            float a[8], b[8];
            *(float4*)&a[0] = *(const float4*)&As[k][ty*8];
            *(float4*)&a[4] = *(const float4*)&As[k][ty*8+4];
            *(float4*)&b[0] = *(const float4*)&Bs[k][tx*8];
            *(float4*)&b[4] = *(const float4*)&Bs[k][tx*8+4];
            #pragma unroll
            for (int i = 0; i < 8; ++i)
                #pragma unroll
                for (int j = 0; j < 8; ++j)
                    acc[i][j] = fmaf(a[i], b[j], acc[i][j]);
        }
    }
    #pragma unroll
    for (int i = 0; i < 8; ++i) {
        float* Crow = C + (size_t)(bm + ty*8 + i) * ldc + bn + tx*8;
        float rb = (EPI == 3) ? bias[bm + ty*8 + i] : 0.f;
        #pragma unroll
        for (int j = 0; j < 8; j += 4) {
            float4 v;
            float t0 = acc[i][j+0], t1 = acc[i][j+1], t2 = acc[i][j+2], t3 = acc[i][j+3];
            if (EPI == 3) {
                t0 = softplus_f(t0 + rb);
                t1 = softplus_f(t1 + rb);
                t2 = softplus_f(t2 + rb);
                t3 = softplus_f(t3 + rb);
            }
            v.x = t0; v.y = t1; v.z = t2; v.w = t3;
            *(float4*)&Crow[j] = v;
        }
    }
}

// depthwise causal conv (D_CONV=4) + silu
__global__ __launch_bounds__(256) void conv_silu_kernel(
    const float* __restrict__ xr, const float* __restrict__ Wc,
    const float* __restrict__ bc, float* __restrict__ u)
{
    int idx = blockIdx.x * 256 + threadIdx.x;
    int d = idx & (DI - 1);
    int t = idx >> 11;
    int l = t & 1023;
    float4 w = *(const float4*)&Wc[d * 4];
    const float wj[4] = {w.x, w.y, w.z, w.w};
    float acc = bc[d];
    #pragma unroll
    for (int j = 0; j < 4; ++j) {
        int ll = l - 3 + j;
        if (ll >= 0) acc += xr[(size_t)(t - 3 + j) * 4096 + d] * wj[j];
    }
    u[idx] = silu_f(acc);
}

// resbuf[t][d] = xr[t][2048+d]
__global__ __launch_bounds__(256) void rescopy_kernel(
    const float* __restrict__ xr, float* __restrict__ resbuf)
{
    int i = blockIdx.x * 256 + threadIdx.x;       // float4 index
    int t = i >> 9, c4 = i & 511;
    ((float4*)resbuf)[(size_t)t * 512 + c4] =
        *(const float4*)&xr[(size_t)t * 4096 + 2048 + c4 * 4];
}

// u[t][d] -> uT[d][t]   (64x64 LDS tiles)
__global__ __launch_bounds__(256) void transpose_u_kernel(
    const float* __restrict__ u, float* __restrict__ uT)
{
    __shared__ float tile[64][68];
    const int t0 = blockIdx.x * 64, d0 = blockIdx.y * 64;
    const int tid = threadIdx.x;
    const int rr = tid >> 4, cc = tid & 15;
    #pragma unroll
    for (int i = 0; i < 4; ++i) {
        int row = rr + i * 16;
        float4 v = *(const float4*)&u[(size_t)(t0 + row) * 2048 + d0 + cc * 4];
        tile[row][cc*4+0] = v.x; tile[row][cc*4+1] = v.y;
        tile[row][cc*4+2] = v.z; tile[row][cc*4+3] = v.w;
    }
    __syncthreads();
    #pragma unroll
    for (int i = 0; i < 4; ++i) {
        int drow = rr + i * 16;
        float4 w;
        w.x = tile[cc*4+0][drow];
        w.y = tile[cc*4+1][drow];
        w.z = tile[cc*4+2][drow];
        w.w = tile[cc*4+3][drow];
        *(float4*)&uT[(size_t)(d0 + drow) * 2048 + t0 + cc * 4] = w;
    }
}

// dbc partial GEMM (fp32 split-K)
__global__ __launch_bounds__(256) void dbc_partial_kernel(
    const float* __restrict__ u, const float* __restrict__ fWx,
    const float* __restrict__ bWx, float* __restrict__ part)
{
    const int rb = blockIdx.x, ks = blockIdx.y, dir = blockIdx.z;
    const float* Wx = dir ? bWx : fWx;
    __shared__ float us[64][33];
    __shared__ float wsh[96][33];
    const int tid = threadIdx.x;
    const int t0 = rb * 64, k0 = ks * 256;
    const int r0 = (tid >> 5) * 8, c0 = (tid & 31) * 3;
    float acc[8][3] = {};
    for (int kk = 0; kk < 256; kk += 32) {
        __syncthreads();
        #pragma unroll
        for (int i = 0; i < 2; ++i) {
            int idx = tid + 256 * i;
            int r = idx >> 3, c4 = (idx & 7) * 4;
            float4 v = *(const float4*)&u[(size_t)(t0 + r) * DI + k0 + kk + c4];
            us[r][c4+0] = v.x; us[r][c4+1] = v.y; us[r][c4+2] = v.z; us[r][c4+3] = v.w;
        }
        #pragma unroll
        for (int i = 0; i < 3; ++i) {
            int idx = tid + 256 * i;
            int e = idx >> 3, c4 = (idx & 7) * 4;
            float4 v = *(const float4*)&Wx[(size_t)e * DI + k0 + kk + c4];
            wsh[e][c4+0] = v.x; wsh[e][c4+1] = v.y; wsh[e][c4+2] = v.z; wsh[e][c4+3] = v.w;
        }
        __syncthreads();
        #pragma unroll
        for (int k = 0; k < 32; ++k) {
            float w0 = wsh[c0][k], w1 = wsh[c0+1][k], w2 = wsh[c0+2][k];
            #pragma unroll
            for (int i = 0; i < 8; ++i) {
                float a = us[r0 + i][k];
                acc[i][0] = fmaf(a, w0, acc[i][0]);
                acc[i][1] = fmaf(a, w1, acc[i][1]);
                acc[i][2] = fmaf(a, w2, acc[i][2]);
            }
        }
    }
    float* pbase = part + (size_t)(dir * 8 + ks) * T_TOK * E96;
    #pragma unroll
    for (int i = 0; i < 8; ++i)
        #pragma unroll
        for (int j = 0; j < 3; ++j)
            pbase[(size_t)(t0 + r0 + i) * E96 + c0 + j] = acc[i][j];
}

// reduce split-K partials; also emit time-major B/C: BCT[dir][t][32]
__global__ __launch_bounds__(256) void dbc_reduce_kernel(
    const float* __restrict__ part, float* __restrict__ dbc,
    float* __restrict__ BCT)
{
    int idx = blockIdx.x * 256 + threadIdx.x;
    int dir = idx / (T_TOK * E96);
    int rem = idx - dir * (T_TOK * E96);
    float s = 0.f;
    #pragma unroll
    for (int ks = 0; ks < 8; ++ks)
        s += part[(size_t)(dir * 8 + ks) * T_TOK * E96 + rem];
    dbc[idx] = s;
    int t = rem / E96;
    int e = rem - t * E96;
    if (e >= 64)
        BCT[((size_t)dir * T_TOK + t) * 32 + (e - 64)] = s;
}

// ---------- time-major chunked scan ----------
// lane = channel d; h[16], A2[16] in registers. R = direction (0 fwd, 1 bwd).
// grid: (DI/256, NCH, 2 batches); launched once per direction.
// deltaT: [dir][d][t_tok], uT: [d][t_tok], BCT: [dir][t_tok][32] (B:0-15, C:16-31)
// Pb/Hb: [z][d][c][16] with z = dir*2+b.

template<int R>
__global__ __launch_bounds__(256) void scan_pass1(
    const float* __restrict__ uT, const float* __restrict__ deltaT,
    const float* __restrict__ BCT,
    const float* __restrict__ fAlog, const float* __restrict__ bAlog,
    float* __restrict__ Pb, float* __restrict__ Hb)
{
    const int tid = threadIdx.x;
    const int d = blockIdx.x * 256 + tid;
    const int c = blockIdx.y;
    const int b = blockIdx.z;
    const int z = R * 2 + b;
    const float* Alog = R ? bAlog : fAlog;
    float A2[16];
    #pragma unroll
    for (int n = 0; n < 16; ++n)
        A2[n] = -__expf(Alog[d * 16 + n]) * 1.44269504f;

    __shared__ float bc[64][32];
    const int tok0 = R ? (960 - c * CH) : (c * CH);
    {
        const float4* src = (const float4*)(BCT + ((size_t)R * T_TOK + b * 1024 + tok0) * 32);
        float4* dst = (float4*)&bc[0][0];
        dst[tid]       = src[tid];
        dst[tid + 256] = src[tid + 256];
    }
    __syncthreads();

    const float* dlrow = deltaT + ((size_t)R * DI + d) * 2048 + b * 1024;
    const float* urow  = uT + (size_t)d * 2048 + b * 1024;
    float h[16];
    #pragma unroll
    for (int n = 0; n < 16; ++n) h[n] = 0.f;
    float S = 0.f;

    for (int g = 0; g < CH / 4; ++g) {
        int sc0 = g * 4;
        int a4 = R ? (tok0 + 60 - sc0) : (tok0 + sc0);
        float4 dl4 = *(const float4*)&dlrow[a4];
        float4 uv4 = *(const float4*)&urow[a4];
        #pragma unroll
        for (int k = 0; k < 4; ++k) {
            int sc = sc0 + k;
            float dl = (&dl4.x)[R ? 3 - k : k];
            float uv = (&uv4.x)[R ? 3 - k : k];
            int j = R ? 63 - sc : sc;
            float dlu = dl * uv;
            float Bv[16];
            *(f32x4*)&Bv[0]  = *(const f32x4*)&bc[j][0];
            *(f32x4*)&Bv[4]  = *(const f32x4*)&bc[j][4];
            *(f32x4*)&Bv[8]  = *(const f32x4*)&bc[j][8];
            *(f32x4*)&Bv[12] = *(const f32x4*)&bc[j][12];
            #pragma unroll
            for (int n = 0; n < 16; ++n)
                h[n] = exp2f(dl * A2[n]) * h[n] + dlu * Bv[n];
            S += dl;
        }
    }
    size_t o = (((size_t)z * DI + d) * NCH + c) * 16;
    #pragma unroll
    for (int n = 0; n < 16; ++n) {
        Pb[o + n] = exp2f(A2[n] * S);
        Hb[o + n] = h[n];
    }
}

// combine chunks: thread per (z,d,ngroup of 4 states)
__global__ __launch_bounds__(256) void scan_pass2(
    float* __restrict__ Pb, const float* __restrict__ Hb)
{
    int idx = blockIdx.x * 256 + threadIdx.x;      // 4*DI*4 = 32768
    int ng = idx & 3;
    int dd = idx >> 2;                              // z*DI + d
    size_t base = (size_t)dd * NCH * 16 + ng * 4;
    f32x4 h = {0.f, 0.f, 0.f, 0.f};
    #pragma unroll
    for (int c = 0; c < NCH; ++c) {
        f32x4 P = *(const f32x4*)&Pb[base + c * 16];
        f32x4 H = *(const f32x4*)&Hb[base + c * 16];
        *(f32x4*)&Pb[base + c * 16] = h;
        h = P * h + H;
    }
}

template<int R>
__global__ __launch_bounds__(256) void scan_pass3(
    const float* __restrict__ uT, const float* __restrict__ deltaT,
    const float* __restrict__ BCT,
    const float* __restrict__ fAlog, const float* __restrict__ fDp,
    const float* __restrict__ bAlog, const float* __restrict__ bDp,
    const float* __restrict__ Hin, float* __restrict__ y)
{
    const int tid = threadIdx.x;
    const int d = blockIdx.x * 256 + tid;
    const int c = blockIdx.y;
    const int b = blockIdx.z;
    const int z = R * 2 + b;
    const float* Alog = R ? bAlog : fAlog;
    const float Dv = (R ? bDp : fDp)[d];
    float A2[16];
    #pragma unroll
    for (int n = 0; n < 16; ++n)
        A2[n] = -__expf(Alog[d * 16 + n]) * 1.44269504f;

    __shared__ float bc[64][32];
    const int tok0 = R ? (960 - c * CH) : (c * CH);
    {
        const float4* src = (const float4*)(BCT + ((size_t)R * T_TOK + b * 1024 + tok0) * 32);
        float4* dst = (float4*)&bc[0][0];
        dst[tid]       = src[tid];
        dst[tid + 256] = src[tid + 256];
    }
    __syncthreads();

    const float* dlrow = deltaT + ((size_t)R * DI + d) * 2048 + b * 1024;
    const float* urow  = uT + (size_t)d * 2048 + b * 1024;
    size_t o = (((size_t)z * DI + d) * NCH + c) * 16;
    float h[16];
    #pragma unroll
    for (int n = 0; n < 16; ++n) h[n] = Hin[o + n];

    for (int g = 0; g < CH / 4; ++g) {
        int sc0 = g * 4;
        int a4 = R ? (tok0 + 60 - sc0) : (tok0 + sc0);
        float4 dl4 = *(const float4*)&dlrow[a4];
        float4 uv4 = *(const float4*)&urow[a4];
        #pragma unroll
        for (int k = 0; k < 4; ++k) {
            int sc = sc0 + k;
            float dl = (&dl4.x)[R ? 3 - k : k];
            float uv = (&uv4.x)[R ? 3 - k : k];
            int j = R ? 63 - sc : sc;
            float dlu = dl * uv;
            float Bv[16], Cv[16];
            *(f32x4*)&Bv[0]  = *(const f32x4*)&bc[j][0];
            *(f32x4*)&Bv[4]  = *(const f32x4*)&bc[j][4];
            *(f32x4*)&Bv[8]  = *(const f32x4*)&bc[j][8];
            *(f32x4*)&Bv[12] = *(const f32x4*)&bc[j][12];
            *(f32x4*)&Cv[0]  = *(const f32x4*)&bc[j][16];
            *(f32x4*)&Cv[4]  = *(const f32x4*)&bc[j][20];
            *(f32x4*)&Cv[8]  = *(const f32x4*)&bc[j][24];
            *(f32x4*)&Cv[12] = *(const f32x4*)&bc[j][28];
            float a0 = 0.f, a1 = 0.f, a2 = 0.f, a3 = 0.f;
            #pragma unroll
            for (int n = 0; n < 4; ++n) {
                h[n]    = exp2f(dl * A2[n])    * h[n]    + dlu * Bv[n];
                h[n+4]  = exp2f(dl * A2[n+4])  * h[n+4]  + dlu * Bv[n+4];
                h[n+8]  = exp2f(dl * A2[n+8])  * h[n+8]  + dlu * Bv[n+8];
                h[n+12] = exp2f(dl * A2[n+12]) * h[n+12] + dlu * Bv[n+12];
                a0 = fmaf(h[n],    Cv[n],    a0);
                a1 = fmaf(h[n+4],  Cv[n+4],  a1);
                a2 = fmaf(h[n+8],  Cv[n+8],  a2);
                a3 = fmaf(h[n+12], Cv[n+12], a3);
            }
            float yv = (a0 + a1) + (a2 + a3) + uv * Dv;
            atomicAdd(&y[((size_t)(b * 1024 + tok0 + j)) * DI + d], yv);
        }
    }
}

__global__ __launch_bounds__(256) void combine_kernel(
    float* __restrict__ y, const float* __restrict__ resbuf)
{
    int idx = blockIdx.x * 256 + threadIdx.x;
    float r = resbuf[idx];
    y[idx] = y[idx] * 0.5f * silu_f(r);
}

extern "C" void kernel_launch(void* const* d_in, const int* in_sizes, int n_in,
                              void* d_out, int out_size, void* d_ws, size_t ws_size,
                              hipStream_t stream)
{
    const float* x      = (const float*)d_in[0];
    const float* W_in   = (const float*)d_in[1];
    const float* W_conv = (const float*)d_in[2];
    const float* b_conv = (const float*)d_in[3];
    const float* W_out  = (const float*)d_in[4];
    const float* fA_log = (const float*)d_in[5];
    const float* fD     = (const float*)d_in[6];
    const float* fWx    = (const float*)d_in[7];
    const float* fWdt   = (const float*)d_in[8];
    const float* fbdt   = (const float*)d_in[9];
    const float* bA_log = (const float*)d_in[10];
    const float* bD     = (const float*)d_in[11];
    const float* bWx    = (const float*)d_in[12];
    const float* bWdt   = (const float*)d_in[13];
    const float* bbdt   = (const float*)d_in[14];

    char* ws = (char*)d_ws;
    const size_t MB = 1ull << 20;
    // region [0,32): xr -> part -> deltaT -> (yh/yl/woh/wol)
    float* xr     = (float*)(ws);
    float* part   = (float*)(ws);                  // 12.6MB, after xr dead
    float* deltaT = (float*)(ws);                  // 32MB, after part dead
    unsigned short* yh  = (unsigned short*)(ws);           // 8MB, after deltaT dead
    unsigned short* yl  = (unsigned short*)(ws + 8*MB);    // 8MB
    unsigned short* woh = (unsigned short*)(ws + 16*MB);   // 4MB
    unsigned short* wol = (unsigned short*)(ws + 20*MB);   // 4MB
    // region [32,48): gemm1 temps -> u
    unsigned short* xh  = (unsigned short*)(ws + 32*MB);   // 4MB
    unsigned short* xl  = (unsigned short*)(ws + 36*MB);   // 4MB
    unsigned short* wih = (unsigned short*)(ws + 40*MB);   // 8MB
    unsigned short* wil = (unsigned short*)(ws + 48*MB);   // 8MB (into [48,56), dead before dbc/BCT/uT)
    float* u      = (float*)(ws + 32*MB);          // 16MB
    float* dbc    = (float*)(ws + 48*MB);          // 1.5MB
    float* BCT    = (float*)(ws + 49*MB + 512*1024); // 0.5MB
    float* uT     = (float*)(ws + 50*MB);          // 16MB
    float* resbuf = (float*)(ws + 66*MB);          // 16MB
    float* Pb     = (float*)(ws + 82*MB);          // 8MB
    float* Hb     = (float*)(ws + 90*MB);          // 8MB
    float* y      = (float*)(ws + 90*MB);          // 16MB, aliases Hb (dead after pass2)
    float* out    = (float*)d_out;

    // 0. split x, W_in
    split_kernel<<<(T_TOK * DM / 4 + 255) / 256, 256, 0, stream>>>(x, xh, xl, T_TOK * DM / 4);
    split_kernel<<<(2 * DI * DM / 4 + 255) / 256, 256, 0, stream>>>(W_in, wih, wil, 2 * DI * DM / 4);

    // 1. xr = x @ W_in^T
    mgemm128<0><<<dim3(4096 / 128, 2048 / 128, 1), 256, 0, stream>>>(
        xh, xl, DM, wih, wil, DM, xr, 4096, DM);

    // 2. u = silu(causal_dwconv(xr[:, :2048]));  resbuf = xr[:, 2048:]
    conv_silu_kernel<<<(T_TOK * DI) / 256, 256, 0, stream>>>(xr, W_conv, b_conv, u);
    rescopy_kernel<<<(T_TOK * DI / 4) / 256, 256, 0, stream>>>(xr, resbuf);

    // 3. dbc[dir] = u @ Wx[dir]^T; also emit time-major B/C
    dbc_partial_kernel<<<dim3(32, 8, 2), 256, 0, stream>>>(u, fWx, bWx, part);
    dbc_reduce_kernel<<<(2 * T_TOK * E96) / 256, 256, 0, stream>>>(part, dbc, BCT);

    // 4. deltaT[dir][d][t] = softplus(Wdt @ dt^T + bdt[d])  (transposed GEMM, row bias)
    sgemm128<3><<<dim3(2048/128, 2048/128), 256, 0, stream>>>(
        fWdt, 64, dbc, 96, deltaT, 2048, 64, fbdt);
    sgemm128<3><<<dim3(2048/128, 2048/128), 256, 0, stream>>>(
        bWdt, 64, dbc + (size_t)T_TOK * E96, 96, deltaT + (size_t)DI * 2048, 2048, 64, bbdt);

    // 5. uT = u^T
    transpose_u_kernel<<<dim3(32, 32), 256, 0, stream>>>(u, uT);

    // 6. chunked scan
    scan_pass1<0><<<dim3(DI / 256, NCH, 2), 256, 0, stream>>>(
        uT, deltaT, BCT, fA_log, bA_log, Pb, Hb);
    scan_pass1<1><<<dim3(DI / 256, NCH, 2), 256, 0, stream>>>(
        uT, deltaT, BCT, fA_log, bA_log, Pb, Hb);
    scan_pass2<<<(4 * DI * 4) / 256, 256, 0, stream>>>(Pb, Hb);
    hipMemsetAsync(y, 0, (size_t)T_TOK * DI * sizeof(float), stream);
    scan_pass3<0><<<dim3(DI / 256, NCH, 2), 256, 0, stream>>>(
        uT, deltaT, BCT, fA_log, fD, bA_log, bD, Pb, y);
    scan_pass3<1><<<dim3(DI / 256, NCH, 2), 256, 0, stream>>>(
        uT, deltaT, BCT, fA_log, fD, bA_log, bD, Pb, y);

    // 7. y = (y_fwd + y_rev) * 0.5 * silu(res)
    combine_kernel<<<(T_TOK * DI) / 256, 256, 0, stream>>>(y, resbuf);

    // 8. out = y @ W_out^T  (split-bf16 MFMA, split-K=2)
    split_kernel<<<(T_TOK * DI / 4 + 255) / 256, 256, 0, stream>>>(y, yh, yl, T_TOK * DI / 4);
    split_kernel<<<(DM * DI / 4 + 255) / 256, 256, 0, stream>>>(W_out, woh, wol, DM * DI / 4);
    hipMemsetAsync(out, 0, (size_t)T_TOK * DM * sizeof(float), stream);
    mgemm128<2><<<dim3(1024 / 128, 2048 / 128, 2), 256, 0, stream>>>(
        yh, yl, DI, woh, wol, DI, out, DM, DI);
}

// Round 5
// 371.276 us; speedup vs baseline: 1.3307x; 1.3307x over previous
//
#include <hip/hip_runtime.h>
#include <hip/hip_bf16.h>
#include <math.h>

#define T_TOK 2048   // BATCH * SEQ
#define DM    1024
#define DI    2048
#define DS    16
#define DR    64
#define E96   96
#define CH    64     // scan chunk length
#define NCH   16     // chunks per sequence (1024 / CH)

typedef __attribute__((ext_vector_type(8))) short bf16x8;
typedef __attribute__((ext_vector_type(4))) float f32x4;

__device__ __forceinline__ float silu_f(float x) {
    return x / (1.f + __expf(-x));
}
__device__ __forceinline__ float softplus_f(float x) {
    return log1pf(__expf(-fabsf(x))) + fmaxf(x, 0.f);
}
__device__ __forceinline__ unsigned short f2bf(float f) {
    unsigned int u = __float_as_uint(f);
    u = (u + 0x7fffu + ((u >> 16) & 1u)) >> 16;
    return (unsigned short)u;
}
__device__ __forceinline__ float bf2f(unsigned short h) {
    return __uint_as_float(((unsigned int)h) << 16);
}
__device__ __forceinline__ void gload16(const unsigned short* g, unsigned short* l) {
    __builtin_amdgcn_global_load_lds((const __attribute__((address_space(1))) void*)g,
                                     (__attribute__((address_space(3))) void*)l, 16, 0, 0);
}

// fp32 -> (hi, lo) bf16 split
__global__ __launch_bounds__(256) void split_kernel(
    const float* __restrict__ in, unsigned short* __restrict__ hi,
    unsigned short* __restrict__ lo, int n4)
{
    int i = blockIdx.x * 256 + threadIdx.x;
    if (i >= n4) return;
    float4 v = ((const float4*)in)[i];
    ushort4 h, l;
    h.x = f2bf(v.x); l.x = f2bf(v.x - bf2f(h.x));
    h.y = f2bf(v.y); l.y = f2bf(v.y - bf2f(h.y));
    h.z = f2bf(v.z); l.z = f2bf(v.z - bf2f(h.z));
    h.w = f2bf(v.w); l.w = f2bf(v.w - bf2f(h.w));
    ((ushort4*)hi)[i] = h;
    ((ushort4*)lo)[i] = l;
}

// Split-bf16 MFMA GEMM (3-term). 128x128 tile, BK=32, 4 waves.
template<int EPI>
__global__ __launch_bounds__(256, 2) void mgemm128(
    const unsigned short* __restrict__ Ah, const unsigned short* __restrict__ Al, int lda,
    const unsigned short* __restrict__ Bh, const unsigned short* __restrict__ Bl, int ldb,
    float* __restrict__ C, int ldc, int K)
{
    __shared__ unsigned short lds[16384];
    const int tid = threadIdx.x;
    const int wid = tid >> 6, lane = tid & 63;
    const int wm = wid >> 1, wn = wid & 1;
    const int bm = blockIdx.y * 128, bn = blockIdx.x * 128;
    const int klen = K / gridDim.z;
    const int kbeg = blockIdx.z * klen, kend = kbeg + klen;

    const int r0  = wid * 32 + (lane >> 2);
    const int r1  = r0 + 16;
    const int sp  = lane & 3;
    const int ks0 = sp ^ ((r0 >> 1) & 3);
    const int ks1 = sp ^ ((r1 >> 1) & 3);
    const size_t ga0 = (size_t)(bm + r0) * lda + ks0 * 8;
    const size_t ga1 = (size_t)(bm + r1) * lda + ks1 * 8;
    const size_t gb0 = (size_t)(bn + r0) * ldb + ks0 * 8;
    const size_t gb1 = (size_t)(bn + r1) * ldb + ks1 * 8;
    unsigned short* lw0 = lds + wid * 1024;
    unsigned short* lw1 = lds + wid * 1024 + 512;

    const int ln = lane & 15, ls = lane >> 4;
    int offA[4], offB[4];
    #pragma unroll
    for (int f = 0; f < 4; ++f) {
        int ra = wm * 64 + f * 16 + ln;
        int rb = wn * 64 + f * 16 + ln;
        offA[f] = ra * 32 + (ls ^ ((ra >> 1) & 3)) * 8;
        offB[f] = rb * 32 + (ls ^ ((rb >> 1) & 3)) * 8;
    }

    f32x4 acc[4][4] = {};
    for (int k0 = kbeg; k0 < kend; k0 += 32) {
        gload16(Ah + ga0 + k0, lw0);
        gload16(Ah + ga1 + k0, lw1);
        gload16(Al + ga0 + k0, lw0 + 4096);
        gload16(Al + ga1 + k0, lw1 + 4096);
        gload16(Bh + gb0 + k0, lw0 + 8192);
        gload16(Bh + gb1 + k0, lw1 + 8192);
        gload16(Bl + gb0 + k0, lw0 + 12288);
        gload16(Bl + gb1 + k0, lw1 + 12288);
        __syncthreads();
        bf16x8 ah[4], al[4], bh[4], bl[4];
        #pragma unroll
        for (int f = 0; f < 4; ++f) {
            ah[f] = *(const bf16x8*)&lds[offA[f]];
            al[f] = *(const bf16x8*)&lds[4096 + offA[f]];
            bh[f] = *(const bf16x8*)&lds[8192 + offB[f]];
            bl[f] = *(const bf16x8*)&lds[12288 + offB[f]];
        }
        #pragma unroll
        for (int i = 0; i < 4; ++i)
            #pragma unroll
            for (int j = 0; j < 4; ++j) {
                acc[i][j] = __builtin_amdgcn_mfma_f32_16x16x32_bf16(ah[i], bh[j], acc[i][j], 0, 0, 0);
                acc[i][j] = __builtin_amdgcn_mfma_f32_16x16x32_bf16(al[i], bh[j], acc[i][j], 0, 0, 0);
                acc[i][j] = __builtin_amdgcn_mfma_f32_16x16x32_bf16(ah[i], bl[j], acc[i][j], 0, 0, 0);
            }
        __syncthreads();
    }

    #pragma unroll
    for (int i = 0; i < 4; ++i) {
        int crow0 = bm + wm * 64 + i * 16 + ls * 4;
        #pragma unroll
        for (int j = 0; j < 4; ++j) {
            int ccol = bn + wn * 64 + j * 16 + ln;
            #pragma unroll
            for (int r = 0; r < 4; ++r) {
                float v = acc[i][j][r];
                if (EPI == 2) atomicAdd(&C[(size_t)(crow0 + r) * ldc + ccol], v);
                else          C[(size_t)(crow0 + r) * ldc + ccol] = v;
            }
        }
    }
}

// deltaT[dir][d][t] = softplus(sum_r Wdt[d][r]*dbc[dir][t][r] + bdt[d])
// skinny-K (K=64) one-shot kernel: 64d x 128t tile, single barrier.
// thread: tx=tid&31 -> t = t0+tx+32j (j<4); ty=tid>>5 -> d = d0+ty*8+i (i<8).
// LDS pad 65 => all reads bank-conflict-free (b: tx+k mod 32; w: 8ty+i+k, bcast).
__global__ __launch_bounds__(256) void delta_kernel(
    const float* __restrict__ fWdt, const float* __restrict__ bWdt,
    const float* __restrict__ fbdt, const float* __restrict__ bbdt,
    const float* __restrict__ dbc, float* __restrict__ deltaT)
{
    const int dir = blockIdx.z;
    const float* Wdt = dir ? bWdt : fWdt;
    const float* bdt = dir ? bbdt : fbdt;
    const float* B = dbc + (size_t)dir * T_TOK * E96;
    __shared__ float wsm[64][65];
    __shared__ float tsm[128][65];
    const int d0 = blockIdx.y * 64, t0 = blockIdx.x * 128;
    const int tid = threadIdx.x;
    #pragma unroll
    for (int i = 0; i < 4; ++i) {
        int idx = tid + i * 256;              // 0..1023
        int r = idx >> 4, c = (idx & 15) * 4;
        float4 v = *(const float4*)&Wdt[(size_t)(d0 + r) * DR + c];
        wsm[r][c] = v.x; wsm[r][c+1] = v.y; wsm[r][c+2] = v.z; wsm[r][c+3] = v.w;
    }
    #pragma unroll
    for (int i = 0; i < 8; ++i) {
        int idx = tid + i * 256;              // 0..2047
        int r = idx >> 4, c = (idx & 15) * 4;
        float4 v = *(const float4*)&B[(size_t)(t0 + r) * E96 + c];
        tsm[r][c] = v.x; tsm[r][c+1] = v.y; tsm[r][c+2] = v.z; tsm[r][c+3] = v.w;
    }
    __syncthreads();
    const int tx = tid & 31, ty = tid >> 5;
    float acc[8][4] = {};
    #pragma unroll 8
    for (int k = 0; k < 64; ++k) {
        float bv[4];
        #pragma unroll
        for (int j = 0; j < 4; ++j) bv[j] = tsm[tx + 32 * j][k];
        #pragma unroll
        for (int i = 0; i < 8; ++i) {
            float w = wsm[ty * 8 + i][k];
            #pragma unroll
            for (int j = 0; j < 4; ++j)
                acc[i][j] = fmaf(w, bv[j], acc[i][j]);
        }
    }
    #pragma unroll
    for (int i = 0; i < 8; ++i) {
        int d = d0 + ty * 8 + i;
        float bias = bdt[d];
        float* drow = deltaT + ((size_t)dir * DI + d) * 2048 + t0;
        #pragma unroll
        for (int j = 0; j < 4; ++j)
            drow[tx + 32 * j] = softplus_f(acc[i][j] + bias);
    }
}

// depthwise causal conv (D_CONV=4) + silu
__global__ __launch_bounds__(256) void conv_silu_kernel(
    const float* __restrict__ xr, const float* __restrict__ Wc,
    const float* __restrict__ bc, float* __restrict__ u)
{
    int idx = blockIdx.x * 256 + threadIdx.x;
    int d = idx & (DI - 1);
    int t = idx >> 11;
    int l = t & 1023;
    float4 w = *(const float4*)&Wc[d * 4];
    const float wj[4] = {w.x, w.y, w.z, w.w};
    float acc = bc[d];
    #pragma unroll
    for (int j = 0; j < 4; ++j) {
        int ll = l - 3 + j;
        if (ll >= 0) acc += xr[(size_t)(t - 3 + j) * 4096 + d] * wj[j];
    }
    u[idx] = silu_f(acc);
}

// resbuf[t][d] = xr[t][2048+d]
__global__ __launch_bounds__(256) void rescopy_kernel(
    const float* __restrict__ xr, float* __restrict__ resbuf)
{
    int i = blockIdx.x * 256 + threadIdx.x;
    int t = i >> 9, c4 = i & 511;
    ((float4*)resbuf)[(size_t)t * 512 + c4] =
        *(const float4*)&xr[(size_t)t * 4096 + 2048 + c4 * 4];
}

// u[t][d] -> uT[d][t]
__global__ __launch_bounds__(256) void transpose_u_kernel(
    const float* __restrict__ u, float* __restrict__ uT)
{
    __shared__ float tile[64][68];
    const int t0 = blockIdx.x * 64, d0 = blockIdx.y * 64;
    const int tid = threadIdx.x;
    const int rr = tid >> 4, cc = tid & 15;
    #pragma unroll
    for (int i = 0; i < 4; ++i) {
        int row = rr + i * 16;
        float4 v = *(const float4*)&u[(size_t)(t0 + row) * 2048 + d0 + cc * 4];
        tile[row][cc*4+0] = v.x; tile[row][cc*4+1] = v.y;
        tile[row][cc*4+2] = v.z; tile[row][cc*4+3] = v.w;
    }
    __syncthreads();
    #pragma unroll
    for (int i = 0; i < 4; ++i) {
        int drow = rr + i * 16;
        float4 w;
        w.x = tile[cc*4+0][drow];
        w.y = tile[cc*4+1][drow];
        w.z = tile[cc*4+2][drow];
        w.w = tile[cc*4+3][drow];
        *(float4*)&uT[(size_t)(d0 + drow) * 2048 + t0 + cc * 4] = w;
    }
}

// dbc partial GEMM (fp32 split-K)
__global__ __launch_bounds__(256) void dbc_partial_kernel(
    const float* __restrict__ u, const float* __restrict__ fWx,
    const float* __restrict__ bWx, float* __restrict__ part)
{
    const int rb = blockIdx.x, ks = blockIdx.y, dir = blockIdx.z;
    const float* Wx = dir ? bWx : fWx;
    __shared__ float us[64][33];
    __shared__ float wsh[96][33];
    const int tid = threadIdx.x;
    const int t0 = rb * 64, k0 = ks * 256;
    const int r0 = (tid >> 5) * 8, c0 = (tid & 31) * 3;
    float acc[8][3] = {};
    for (int kk = 0; kk < 256; kk += 32) {
        __syncthreads();
        #pragma unroll
        for (int i = 0; i < 2; ++i) {
            int idx = tid + 256 * i;
            int r = idx >> 3, c4 = (idx & 7) * 4;
            float4 v = *(const float4*)&u[(size_t)(t0 + r) * DI + k0 + kk + c4];
            us[r][c4+0] = v.x; us[r][c4+1] = v.y; us[r][c4+2] = v.z; us[r][c4+3] = v.w;
        }
        #pragma unroll
        for (int i = 0; i < 3; ++i) {
            int idx = tid + 256 * i;
            int e = idx >> 3, c4 = (idx & 7) * 4;
            float4 v = *(const float4*)&Wx[(size_t)e * DI + k0 + kk + c4];
            wsh[e][c4+0] = v.x; wsh[e][c4+1] = v.y; wsh[e][c4+2] = v.z; wsh[e][c4+3] = v.w;
        }
        __syncthreads();
        #pragma unroll
        for (int k = 0; k < 32; ++k) {
            float w0 = wsh[c0][k], w1 = wsh[c0+1][k], w2 = wsh[c0+2][k];
            #pragma unroll
            for (int i = 0; i < 8; ++i) {
                float a = us[r0 + i][k];
                acc[i][0] = fmaf(a, w0, acc[i][0]);
                acc[i][1] = fmaf(a, w1, acc[i][1]);
                acc[i][2] = fmaf(a, w2, acc[i][2]);
            }
        }
    }
    float* pbase = part + (size_t)(dir * 8 + ks) * T_TOK * E96;
    #pragma unroll
    for (int i = 0; i < 8; ++i)
        #pragma unroll
        for (int j = 0; j < 3; ++j)
            pbase[(size_t)(t0 + r0 + i) * E96 + c0 + j] = acc[i][j];
}

// reduce split-K partials; also emit time-major B/C: BCT[dir][t][32]
__global__ __launch_bounds__(256) void dbc_reduce_kernel(
    const float* __restrict__ part, float* __restrict__ dbc,
    float* __restrict__ BCT)
{
    int idx = blockIdx.x * 256 + threadIdx.x;
    int dir = idx / (T_TOK * E96);
    int rem = idx - dir * (T_TOK * E96);
    float s = 0.f;
    #pragma unroll
    for (int ks = 0; ks < 8; ++ks)
        s += part[(size_t)(dir * 8 + ks) * T_TOK * E96 + rem];
    dbc[idx] = s;
    int t = rem / E96;
    int e = rem - t * E96;
    if (e >= 64)
        BCT[((size_t)dir * T_TOK + t) * 32 + (e - 64)] = s;
}

// ---------- time-major chunked scan ----------
template<int R>
__global__ __launch_bounds__(256) void scan_pass1(
    const float* __restrict__ uT, const float* __restrict__ deltaT,
    const float* __restrict__ BCT,
    const float* __restrict__ fAlog, const float* __restrict__ bAlog,
    float* __restrict__ Pb, float* __restrict__ Hb)
{
    const int tid = threadIdx.x;
    const int d = blockIdx.x * 256 + tid;
    const int c = blockIdx.y;
    const int b = blockIdx.z;
    const int z = R * 2 + b;
    const float* Alog = R ? bAlog : fAlog;
    float A2[16];
    #pragma unroll
    for (int n = 0; n < 16; ++n)
        A2[n] = -__expf(Alog[d * 16 + n]) * 1.44269504f;

    __shared__ float bc[64][32];
    const int tok0 = R ? (960 - c * CH) : (c * CH);
    {
        const float4* src = (const float4*)(BCT + ((size_t)R * T_TOK + b * 1024 + tok0) * 32);
        float4* dst = (float4*)&bc[0][0];
        dst[tid]       = src[tid];
        dst[tid + 256] = src[tid + 256];
    }
    __syncthreads();

    const float* dlrow = deltaT + ((size_t)R * DI + d) * 2048 + b * 1024;
    const float* urow  = uT + (size_t)d * 2048 + b * 1024;
    float h[16];
    #pragma unroll
    for (int n = 0; n < 16; ++n) h[n] = 0.f;
    float S = 0.f;

    for (int g = 0; g < CH / 4; ++g) {
        int sc0 = g * 4;
        int a4 = R ? (tok0 + 60 - sc0) : (tok0 + sc0);
        float4 dl4 = *(const float4*)&dlrow[a4];
        float4 uv4 = *(const float4*)&urow[a4];
        #pragma unroll
        for (int k = 0; k < 4; ++k) {
            int sc = sc0 + k;
            float dl = (&dl4.x)[R ? 3 - k : k];
            float uv = (&uv4.x)[R ? 3 - k : k];
            int j = R ? 63 - sc : sc;
            float dlu = dl * uv;
            float Bv[16];
            *(f32x4*)&Bv[0]  = *(const f32x4*)&bc[j][0];
            *(f32x4*)&Bv[4]  = *(const f32x4*)&bc[j][4];
            *(f32x4*)&Bv[8]  = *(const f32x4*)&bc[j][8];
            *(f32x4*)&Bv[12] = *(const f32x4*)&bc[j][12];
            #pragma unroll
            for (int n = 0; n < 16; ++n)
                h[n] = exp2f(dl * A2[n]) * h[n] + dlu * Bv[n];
            S += dl;
        }
    }
    size_t o = (((size_t)z * DI + d) * NCH + c) * 16;
    #pragma unroll
    for (int n = 0; n < 16; ++n) {
        Pb[o + n] = exp2f(A2[n] * S);
        Hb[o + n] = h[n];
    }
}

__global__ __launch_bounds__(256) void scan_pass2(
    float* __restrict__ Pb, const float* __restrict__ Hb)
{
    int idx = blockIdx.x * 256 + threadIdx.x;
    int ng = idx & 3;
    int dd = idx >> 2;
    size_t base = (size_t)dd * NCH * 16 + ng * 4;
    f32x4 h = {0.f, 0.f, 0.f, 0.f};
    #pragma unroll
    for (int c = 0; c < NCH; ++c) {
        f32x4 P = *(const f32x4*)&Pb[base + c * 16];
        f32x4 H = *(const f32x4*)&Hb[base + c * 16];
        *(f32x4*)&Pb[base + c * 16] = h;
        h = P * h + H;
    }
}

// pass3: R=0 -> y = y_fwd (plain store).
// R=1 -> final = (y_fwd + y_bwd)*0.5*silu(res); emit bf16 hi/lo split directly.
template<int R>
__global__ __launch_bounds__(256) void scan_pass3(
    const float* __restrict__ uT, const float* __restrict__ deltaT,
    const float* __restrict__ BCT,
    const float* __restrict__ fAlog, const float* __restrict__ fDp,
    const float* __restrict__ bAlog, const float* __restrict__ bDp,
    const float* __restrict__ Hin, float* __restrict__ y,
    const float* __restrict__ resbuf,
    unsigned short* __restrict__ yh, unsigned short* __restrict__ yl)
{
    const int tid = threadIdx.x;
    const int d = blockIdx.x * 256 + tid;
    const int c = blockIdx.y;
    const int b = blockIdx.z;
    const int z = R * 2 + b;
    const float* Alog = R ? bAlog : fAlog;
    const float Dv = (R ? bDp : fDp)[d];
    float A2[16];
    #pragma unroll
    for (int n = 0; n < 16; ++n)
        A2[n] = -__expf(Alog[d * 16 + n]) * 1.44269504f;

    __shared__ float bc[64][32];
    const int tok0 = R ? (960 - c * CH) : (c * CH);
    {
        const float4* src = (const float4*)(BCT + ((size_t)R * T_TOK + b * 1024 + tok0) * 32);
        float4* dst = (float4*)&bc[0][0];
        dst[tid]       = src[tid];
        dst[tid + 256] = src[tid + 256];
    }
    __syncthreads();

    const float* dlrow = deltaT + ((size_t)R * DI + d) * 2048 + b * 1024;
    const float* urow  = uT + (size_t)d * 2048 + b * 1024;
    size_t o = (((size_t)z * DI + d) * NCH + c) * 16;
    float h[16];
    #pragma unroll
    for (int n = 0; n < 16; ++n) h[n] = Hin[o + n];

    for (int g = 0; g < CH / 4; ++g) {
        int sc0 = g * 4;
        int a4 = R ? (tok0 + 60 - sc0) : (tok0 + sc0);
        float4 dl4 = *(const float4*)&dlrow[a4];
        float4 uv4 = *(const float4*)&urow[a4];
        #pragma unroll
        for (int k = 0; k < 4; ++k) {
            int sc = sc0 + k;
            float dl = (&dl4.x)[R ? 3 - k : k];
            float uv = (&uv4.x)[R ? 3 - k : k];
            int j = R ? 63 - sc : sc;
            float dlu = dl * uv;
            float Bv[16], Cv[16];
            *(f32x4*)&Bv[0]  = *(const f32x4*)&bc[j][0];
            *(f32x4*)&Bv[4]  = *(const f32x4*)&bc[j][4];
            *(f32x4*)&Bv[8]  = *(const f32x4*)&bc[j][8];
            *(f32x4*)&Bv[12] = *(const f32x4*)&bc[j][12];
            *(f32x4*)&Cv[0]  = *(const f32x4*)&bc[j][16];
            *(f32x4*)&Cv[4]  = *(const f32x4*)&bc[j][20];
            *(f32x4*)&Cv[8]  = *(const f32x4*)&bc[j][24];
            *(f32x4*)&Cv[12] = *(const f32x4*)&bc[j][28];
            float a0 = 0.f, a1 = 0.f, a2 = 0.f, a3 = 0.f;
            #pragma unroll
            for (int n = 0; n < 4; ++n) {
                h[n]    = exp2f(dl * A2[n])    * h[n]    + dlu * Bv[n];
                h[n+4]  = exp2f(dl * A2[n+4])  * h[n+4]  + dlu * Bv[n+4];
                h[n+8]  = exp2f(dl * A2[n+8])  * h[n+8]  + dlu * Bv[n+8];
                h[n+12] = exp2f(dl * A2[n+12]) * h[n+12] + dlu * Bv[n+12];
                a0 = fmaf(h[n],    Cv[n],    a0);
                a1 = fmaf(h[n+4],  Cv[n+4],  a1);
                a2 = fmaf(h[n+8],  Cv[n+8],  a2);
                a3 = fmaf(h[n+12], Cv[n+12], a3);
            }
            float yv = (a0 + a1) + (a2 + a3) + uv * Dv;
            size_t idx = ((size_t)(b * 1024 + tok0 + j)) * DI + d;
            if (R == 0) {
                y[idx] = yv;
            } else {
                float fin = (y[idx] + yv) * 0.5f * silu_f(resbuf[idx]);
                unsigned short hi = f2bf(fin);
                yh[idx] = hi;
                yl[idx] = f2bf(fin - bf2f(hi));
            }
        }
    }
}

extern "C" void kernel_launch(void* const* d_in, const int* in_sizes, int n_in,
                              void* d_out, int out_size, void* d_ws, size_t ws_size,
                              hipStream_t stream)
{
    const float* x      = (const float*)d_in[0];
    const float* W_in   = (const float*)d_in[1];
    const float* W_conv = (const float*)d_in[2];
    const float* b_conv = (const float*)d_in[3];
    const float* W_out  = (const float*)d_in[4];
    const float* fA_log = (const float*)d_in[5];
    const float* fD     = (const float*)d_in[6];
    const float* fWx    = (const float*)d_in[7];
    const float* fWdt   = (const float*)d_in[8];
    const float* fbdt   = (const float*)d_in[9];
    const float* bA_log = (const float*)d_in[10];
    const float* bD     = (const float*)d_in[11];
    const float* bWx    = (const float*)d_in[12];
    const float* bWdt   = (const float*)d_in[13];
    const float* bbdt   = (const float*)d_in[14];

    char* ws = (char*)d_ws;
    const size_t MB = 1ull << 20;
    // region [0,32): xr -> part -> deltaT -> (yh/yl then woh/wol)
    float* xr     = (float*)(ws);
    float* part   = (float*)(ws);
    float* deltaT = (float*)(ws);
    unsigned short* yh  = (unsigned short*)(ws);           // 8MB (over deltaT dir0, safe)
    unsigned short* yl  = (unsigned short*)(ws + 8*MB);    // 8MB
    unsigned short* woh = (unsigned short*)(ws + 16*MB);   // 4MB (after pass3<1> done)
    unsigned short* wol = (unsigned short*)(ws + 20*MB);   // 4MB
    // region [32,48): gemm1 temps -> u
    unsigned short* xh  = (unsigned short*)(ws + 32*MB);
    unsigned short* xl  = (unsigned short*)(ws + 36*MB);
    unsigned short* wih = (unsigned short*)(ws + 40*MB);
    unsigned short* wil = (unsigned short*)(ws + 48*MB);   // dead before dbc/BCT/uT
    float* u      = (float*)(ws + 32*MB);
    float* dbc    = (float*)(ws + 48*MB);
    float* BCT    = (float*)(ws + 49*MB + 512*1024);
    float* uT     = (float*)(ws + 50*MB);
    float* resbuf = (float*)(ws + 66*MB);
    float* Pb     = (float*)(ws + 82*MB);
    float* Hb     = (float*)(ws + 90*MB);
    float* y      = (float*)(ws + 90*MB);   // aliases Hb (dead after pass2)
    float* out    = (float*)d_out;

    // 0. split x, W_in
    split_kernel<<<(T_TOK * DM / 4 + 255) / 256, 256, 0, stream>>>(x, xh, xl, T_TOK * DM / 4);
    split_kernel<<<(2 * DI * DM / 4 + 255) / 256, 256, 0, stream>>>(W_in, wih, wil, 2 * DI * DM / 4);

    // 1. xr = x @ W_in^T
    mgemm128<0><<<dim3(4096 / 128, 2048 / 128, 1), 256, 0, stream>>>(
        xh, xl, DM, wih, wil, DM, xr, 4096, DM);

    // 2. u = silu(causal_dwconv(xr[:, :2048]));  resbuf = xr[:, 2048:]
    conv_silu_kernel<<<(T_TOK * DI) / 256, 256, 0, stream>>>(xr, W_conv, b_conv, u);
    rescopy_kernel<<<(T_TOK * DI / 4) / 256, 256, 0, stream>>>(xr, resbuf);

    // 3. dbc[dir] = u @ Wx[dir]^T; also emit time-major B/C
    dbc_partial_kernel<<<dim3(32, 8, 2), 256, 0, stream>>>(u, fWx, bWx, part);
    dbc_reduce_kernel<<<(2 * T_TOK * E96) / 256, 256, 0, stream>>>(part, dbc, BCT);

    // 4. deltaT = softplus(Wdt @ dt^T + bdt)  — skinny-K dedicated kernel
    delta_kernel<<<dim3(T_TOK / 128, DI / 64, 2), 256, 0, stream>>>(
        fWdt, bWdt, fbdt, bbdt, dbc, deltaT);

    // 5. uT = u^T
    transpose_u_kernel<<<dim3(32, 32), 256, 0, stream>>>(u, uT);

    // 6. chunked scan; pass3<1> fuses combine + bf16 split of y
    scan_pass1<0><<<dim3(DI / 256, NCH, 2), 256, 0, stream>>>(
        uT, deltaT, BCT, fA_log, bA_log, Pb, Hb);
    scan_pass1<1><<<dim3(DI / 256, NCH, 2), 256, 0, stream>>>(
        uT, deltaT, BCT, fA_log, bA_log, Pb, Hb);
    scan_pass2<<<(4 * DI * 4) / 256, 256, 0, stream>>>(Pb, Hb);
    scan_pass3<0><<<dim3(DI / 256, NCH, 2), 256, 0, stream>>>(
        uT, deltaT, BCT, fA_log, fD, bA_log, bD, Pb, y, resbuf, yh, yl);
    scan_pass3<1><<<dim3(DI / 256, NCH, 2), 256, 0, stream>>>(
        uT, deltaT, BCT, fA_log, fD, bA_log, bD, Pb, y, resbuf, yh, yl);

    // 7. out = y @ W_out^T  (split-bf16 MFMA, split-K=2)
    split_kernel<<<(DM * DI / 4 + 255) / 256, 256, 0, stream>>>(W_out, woh, wol, DM * DI / 4);
    hipMemsetAsync(out, 0, (size_t)T_TOK * DM * sizeof(float), stream);
    mgemm128<2><<<dim3(1024 / 128, 2048 / 128, 2), 256, 0, stream>>>(
        yh, yl, DI, woh, wol, DI, out, DM, DI);
}